// Round 2
// baseline (27052.512 us; speedup 1.0000x reference)
//
#include <hip/hip_runtime.h>

#define NBLK 256
#define NTHR 512

// workspace layout (floats)
#define OFF_G    0            // 1024*1024
#define OFF_QT   1048576      // 128*1024
#define OFF_Y    1179648      // 128*1024 (atomic-accumulated)
#define OFF_C    1703936      // 128*128 (atomic-accumulated)
#define OFF_RP   1851392      // Rpart[1024][16]
#define OFF_ACC  1867776      // 4 floats
#define OFF_BAR  1867792      // 144 counter lines (stride 16 u32 = 64B)

#define BAR_A 0    // 64 lines, 256 arrive / 256 wait
#define BAR_B 64   // 64 lines, 256 arrive / 32 wait
#define BAR_C 128  // 8 lines, 32 arrive / {32,16} wait
#define BAR_E 136  // 4 lines, 16 arrive / 256 wait

typedef float v4f __attribute__((ext_vector_type(4)));
typedef float v2f __attribute__((ext_vector_type(2)));

// ---- batched agent-coherent loads (sc1), wait included ----
__device__ __forceinline__ void cld4_8(v4f& a, v4f& b, v4f& c, v4f& d,
                                       v4f& e, v4f& f, v4f& g, v4f& h,
                                       const float* pa, const float* pb,
                                       const float* pc, const float* pd,
                                       const float* pe, const float* pf,
                                       const float* pg, const float* ph) {
    asm volatile("global_load_dwordx4 %0, %8, off sc1\n\t"
                 "global_load_dwordx4 %1, %9, off sc1\n\t"
                 "global_load_dwordx4 %2, %10, off sc1\n\t"
                 "global_load_dwordx4 %3, %11, off sc1\n\t"
                 "global_load_dwordx4 %4, %12, off sc1\n\t"
                 "global_load_dwordx4 %5, %13, off sc1\n\t"
                 "global_load_dwordx4 %6, %14, off sc1\n\t"
                 "global_load_dwordx4 %7, %15, off sc1\n\t"
                 "s_waitcnt vmcnt(0)"
                 : "=&v"(a), "=&v"(b), "=&v"(c), "=&v"(d),
                   "=&v"(e), "=&v"(f), "=&v"(g), "=&v"(h)
                 : "v"(pa), "v"(pb), "v"(pc), "v"(pd),
                   "v"(pe), "v"(pf), "v"(pg), "v"(ph) : "memory");
}
__device__ __forceinline__ void cld4_4(v4f& a, v4f& b, v4f& c, v4f& d,
                                       const float* pa, const float* pb,
                                       const float* pc, const float* pd) {
    asm volatile("global_load_dwordx4 %0, %4, off sc1\n\t"
                 "global_load_dwordx4 %1, %5, off sc1\n\t"
                 "global_load_dwordx4 %2, %6, off sc1\n\t"
                 "global_load_dwordx4 %3, %7, off sc1\n\t"
                 "s_waitcnt vmcnt(0)"
                 : "=&v"(a), "=&v"(b), "=&v"(c), "=&v"(d)
                 : "v"(pa), "v"(pb), "v"(pc), "v"(pd) : "memory");
}
__device__ __forceinline__ void cld4_2(v4f& a, v4f& b,
                                       const float* pa, const float* pb) {
    asm volatile("global_load_dwordx4 %0, %2, off sc1\n\t"
                 "global_load_dwordx4 %1, %3, off sc1\n\t"
                 "s_waitcnt vmcnt(0)"
                 : "=&v"(a), "=&v"(b) : "v"(pa), "v"(pb) : "memory");
}
__device__ __forceinline__ void cld1_4(float& a, float& b, float& c, float& d,
                                       const float* pa, const float* pb,
                                       const float* pc, const float* pd) {
    asm volatile("global_load_dword %0, %4, off sc1\n\t"
                 "global_load_dword %1, %5, off sc1\n\t"
                 "global_load_dword %2, %6, off sc1\n\t"
                 "global_load_dword %3, %7, off sc1\n\t"
                 "s_waitcnt vmcnt(0)"
                 : "=&v"(a), "=&v"(b), "=&v"(c), "=&v"(d)
                 : "v"(pa), "v"(pb), "v"(pc), "v"(pd) : "memory");
}
// ---- issue-only variants ----
__device__ __forceinline__ void iss2(v4f& a, v4f& b,
                                     const float* pa, const float* pb) {
    asm volatile("global_load_dwordx4 %0, %2, off sc1\n\t"
                 "global_load_dwordx4 %1, %3, off sc1"
                 : "=&v"(a), "=&v"(b) : "v"(pa), "v"(pb) : "memory");
}
__device__ __forceinline__ void issY(v2f& q, v4f& g,
                                     const float* pq, const float* pg) {
    asm volatile("global_load_dwordx2 %0, %2, off sc1\n\t"
                 "global_load_dwordx4 %1, %3, off sc1"
                 : "=&v"(q), "=&v"(g) : "v"(pq), "v"(pg) : "memory");
}
__device__ __forceinline__ void issS8(float& a, float& b, float& c, float& d,
                                      float& e, float& f, float& g, float& h,
                                      const float* pa, const float* pb,
                                      const float* pc, const float* pd,
                                      const float* pe, const float* pf,
                                      const float* pg, const float* ph) {
    asm volatile("global_load_dword %0, %8, off sc1\n\t"
                 "global_load_dword %1, %9, off sc1\n\t"
                 "global_load_dword %2, %10, off sc1\n\t"
                 "global_load_dword %3, %11, off sc1\n\t"
                 "global_load_dword %4, %12, off sc1\n\t"
                 "global_load_dword %5, %13, off sc1\n\t"
                 "global_load_dword %6, %14, off sc1\n\t"
                 "global_load_dword %7, %15, off sc1"
                 : "=&v"(a), "=&v"(b), "=&v"(c), "=&v"(d),
                   "=&v"(e), "=&v"(f), "=&v"(g), "=&v"(h)
                 : "v"(pa), "v"(pb), "v"(pc), "v"(pd),
                   "v"(pe), "v"(pf), "v"(pg), "v"(ph) : "memory");
}
// ---- counted-vmcnt waits (tie the staged regs) ----
#define DEF_WT2(NAME, NSTR) \
__device__ __forceinline__ void NAME(v4f& a, v4f& b) { \
    asm volatile("s_waitcnt vmcnt(" NSTR ")" : "+v"(a), "+v"(b) :: "memory"); }
DEF_WT2(wt2_6, "6")
DEF_WT2(wt2_4, "4")
DEF_WT2(wt2_2, "2")
DEF_WT2(wt2_0, "0")
#define DEF_WTY(NAME, NSTR) \
__device__ __forceinline__ void NAME(v2f& q, v4f& g) { \
    asm volatile("s_waitcnt vmcnt(" NSTR ")" : "+v"(q), "+v"(g) :: "memory"); }
DEF_WTY(wtY_6, "6")
DEF_WTY(wtY_4, "4")
DEF_WTY(wtY_2, "2")
DEF_WTY(wtY_0, "0")
__device__ __forceinline__ void wtA16(float* a) {
    asm volatile("s_waitcnt vmcnt(0)"
                 : "+v"(a[0]), "+v"(a[1]), "+v"(a[2]), "+v"(a[3]),
                   "+v"(a[4]), "+v"(a[5]), "+v"(a[6]), "+v"(a[7]),
                   "+v"(a[8]), "+v"(a[9]), "+v"(a[10]), "+v"(a[11]),
                   "+v"(a[12]), "+v"(a[13]), "+v"(a[14]), "+v"(a[15])
                 :: "memory");
}

// barrier that waits LDS ops only — in-flight global loads survive it
__device__ __forceinline__ void syncL() {
    asm volatile("s_waitcnt lgkmcnt(0)" ::: "memory");
    __builtin_amdgcn_s_barrier();
    asm volatile("" ::: "memory");
}

// ---- coherent scalar/pair stores + loads ----
__device__ __forceinline__ void ast2(float* p, float a, float b) {
    union { unsigned long long u; float f[2]; } c; c.f[0] = a; c.f[1] = b;
    __hip_atomic_store((unsigned long long*)p, c.u,
                       __ATOMIC_RELAXED, __HIP_MEMORY_SCOPE_AGENT);
}
__device__ __forceinline__ float ald(const float* p) {
    return __hip_atomic_load(p, __ATOMIC_RELAXED, __HIP_MEMORY_SCOPE_AGENT);
}
__device__ __forceinline__ void ast(float* p, float x) {
    __hip_atomic_store(p, x, __ATOMIC_RELAXED, __HIP_MEMORY_SCOPE_AGENT);
}

__device__ __forceinline__ void bar_arrive(unsigned* bb, int line) {
    __syncthreads();
    if (threadIdx.x == 0)
        __hip_atomic_fetch_add(bb + line * 16, 1u,
                               __ATOMIC_RELAXED, __HIP_MEMORY_SCOPE_AGENT);
}
__device__ __forceinline__ void bar_wait(unsigned* bb, int wbase, int nlines,
                                         unsigned tgt) {
    if ((int)threadIdx.x < nlines) {
        while (__hip_atomic_load(bb + (wbase + threadIdx.x) * 16,
                                 __ATOMIC_RELAXED, __HIP_MEMORY_SCOPE_AGENT) < tgt)
            __builtin_amdgcn_s_sleep(1);
    }
    __builtin_amdgcn_s_waitcnt(0);
    __syncthreads();
}

union Smem {
    struct { float As[2][32][68]; float Bs[2][32][68]; float Rs[64][17]; } gg;
    struct { float Cs[128][129]; float inv_d[2][16]; float irs[128];
             float Xs[16][64]; } chol;                                   // 70784 B
    struct { float Ri[1024]; float red[512]; float As[2][32][36];
             float Bs[2][32][68]; } gy;
    struct { float As[32][68]; float Bs[32][68]; float red[512]; } tb;
    float red[512];
};

__device__ __forceinline__ void dev_match(Smem* sm, const float* t1, const float* t2,
                                          float* accb, int w) {
    int tid = threadIdx.x;
    const float4* a = (const float4*)t1;
    const float4* b = (const float4*)t2;
    float s = 0.f;
    for (int i = w * 512 + tid; i < 1048576; i += 218 * 512) {
        float4 x = a[i], y = b[i];
        float d0 = x.x - y.x, d1 = x.y - y.y, d2 = x.z - y.z, d3 = x.w - y.w;
        s += d0 * d0 + d1 * d1 + d2 * d2 + d3 * d3;
    }
    sm->red[tid] = s; __syncthreads();
    for (int w2 = 256; w2 > 0; w2 >>= 1) {
        if (tid < w2) sm->red[tid] += sm->red[tid + w2];
        __syncthreads();
    }
    if (tid == 0) atomicAdd(&accb[0], sm->red[0]);
    __syncthreads();
}

__device__ __forceinline__ void dev_range(Smem* sm, const float* params, const float* tmin,
                                          const float* tmax, float* accb) {
    int tid = threadIdx.x;
    float a = tmin[0], b = tmax[0];
    const float d = 0.01f;
    float s = 0.f;
    for (int i = tid; i < 128 * 17; i += 512) {
        float p = params[i];
        float r1 = (p - a - d) / (-d);
        float r2 = (p - b + d) / d;
        s += fmaxf(fmaxf(r1, r2), 0.f);
    }
    sm->red[tid] = s; __syncthreads();
    for (int w = 256; w > 0; w >>= 1) {
        if (tid < w) sm->red[tid] += sm->red[tid + w];
        __syncthreads();
    }
    if (tid == 0) atomicAdd(&accb[1], sm->red[0]);
    __syncthreads();
}

__device__ __forceinline__ void dev_sumsq(Smem* sm, const float* X, float* accb, int w) {
    int tid = threadIdx.x;
    float s = 0.f;
    for (int i = w * 512 + tid; i < 131072; i += 2048) { float v = X[i]; s += v * v; }
    sm->red[tid] = s; __syncthreads();
    for (int w2 = 256; w2 > 0; w2 >>= 1) {
        if (tid < w2) sm->red[tid] += sm->red[tid + w2];
        __syncthreads();
    }
    if (tid == 0) atomicAdd(&accb[3], sm->red[0]);
    __syncthreads();
}

#define SY_BODY(CK, RA, RB, WT) do { \
    WT; \
    sm->gg.As[(CK) & 1][kg + 0][p] = RA.x; sm->gg.As[(CK) & 1][kg + 1][p] = RA.y; \
    sm->gg.As[(CK) & 1][kg + 2][p] = RA.z; sm->gg.As[(CK) & 1][kg + 3][p] = RA.w; \
    sm->gg.Bs[(CK) & 1][kg + 0][p] = RB.x; sm->gg.Bs[(CK) & 1][kg + 1][p] = RB.y; \
    sm->gg.Bs[(CK) & 1][kg + 2][p] = RB.z; sm->gg.Bs[(CK) & 1][kg + 3][p] = RB.w; \
    syncL(); \
    for (int k = 0; k < 32; ++k) { \
        float2 a2 = *(const float2*)&sm->gg.As[(CK) & 1][k][ty * 2]; \
        float4 b4 = *(const float4*)&sm->gg.Bs[(CK) & 1][k][tx * 4]; \
        acc[0][0] += a2.x * b4.x; acc[0][1] += a2.x * b4.y; \
        acc[0][2] += a2.x * b4.z; acc[0][3] += a2.x * b4.w; \
        acc[1][0] += a2.y * b4.x; acc[1][1] += a2.y * b4.y; \
        acc[1][2] += a2.y * b4.z; acc[1][3] += a2.y * b4.w; \
    } \
} while (0)

// C += A-tile(64 rows p0) x B-tile(64 rows q0) over K-chunk z of 128 (atomicAdd).
// Depth-4 counted-vmcnt pipeline, dbuf LDS, lgkm-only barriers.
__device__ __forceinline__ void dev_syrk(Smem* sm, const float* A, const float* B,
                                         float* C, int bid) {
    int tid = threadIdx.x;
    int q0 = (bid & 1) * 64, p0 = ((bid >> 1) & 1) * 64, z = bid >> 2;
    int kc0 = z * 128;
    int p = tid & 63, kg = (tid >> 6) * 4;
    int tx = tid & 15, ty = tid >> 4;
    float acc[2][4] = {};
    v4f a0r, b0r, a1r, b1r, a2r, b2r, a3r, b3r;
    const float* Ab = &A[(p0 + p) * 1024 + kc0 + kg];
    const float* Bb = &B[(q0 + p) * 1024 + kc0 + kg];
    iss2(a0r, b0r, Ab, Bb);
    iss2(a1r, b1r, Ab + 32, Bb + 32);
    iss2(a2r, b2r, Ab + 64, Bb + 64);
    iss2(a3r, b3r, Ab + 96, Bb + 96);
    SY_BODY(0, a0r, b0r, wt2_6(a0r, b0r));
    SY_BODY(1, a1r, b1r, wt2_4(a1r, b1r));
    SY_BODY(2, a2r, b2r, wt2_2(a2r, b2r));
    SY_BODY(3, a3r, b3r, wt2_0(a3r, b3r));
    #pragma unroll
    for (int i = 0; i < 2; ++i)
        #pragma unroll
        for (int j = 0; j < 4; ++j)
            atomicAdd(&C[(p0 + ty * 2 + i) * 128 + q0 + tx * 4 + j], acc[i][j]);
}

// one 16-wide Cholesky panel (columns [kb*16, kb*16+16)), wave 0 only
__device__ __forceinline__ void chol_panel(Smem* sm, int kb, int lane) {
    int k0 = kb * 16;
    float P0[16], P1[16], invs[16];
    #pragma unroll
    for (int u = 0; u < 16; ++u) {
        P0[u] = sm->chol.Cs[lane][k0 + u];
        P1[u] = sm->chol.Cs[lane + 64][k0 + u];
    }
    #pragma unroll
    for (int kk = 0; kk < 16; ++kk) {
        int k = k0 + kk;
        int src = k & 63;
        bool hi = (k >= 64);
        float pr[16];
        #pragma unroll
        for (int u = 0; u < 16; ++u)
            if (u >= kk) pr[u] = __shfl(hi ? P1[u] : P0[u], src);
        float inv = __builtin_amdgcn_rcpf(pr[kk]);
        invs[kk] = inv;
        float f0 = (lane > k) ? P0[kk] * inv : 0.f;
        float f1 = ((lane + 64) > k) ? P1[kk] * inv : 0.f;
        #pragma unroll
        for (int u = kk + 1; u < 16; ++u) {
            P0[u] -= f0 * pr[u];
            P1[u] -= f1 * pr[u];
        }
    }
    #pragma unroll
    for (int u = 0; u < 16; ++u) {
        sm->chol.Cs[lane][k0 + u] = P0[u];
        sm->chol.Cs[lane + 64][k0 + u] = P1[u];
    }
    if (lane == 0) {
        #pragma unroll
        for (int kk = 0; kk < 16; ++kk) sm->chol.inv_d[kb & 1][kk] = invs[kk];
    }
}

// Fused: redundant Cholesky of C (16 blocks, lookahead factor) + forward solve
// for 64 columns each. RHS loads issued before the factor, waited after.
__device__ __forceinline__ void dev_cholTrsm(Smem* sm, const float* C, const float* RHS,
                                             float* Qt, int bid) {
    int tid = threadIdx.x;
    // stage C (32 floats/thread)
    {
        const float* base = C + tid * 32;
        v4f z0, z1, z2, z3, z4, z5, z6, z7;
        cld4_8(z0, z1, z2, z3, z4, z5, z6, z7,
               base, base + 4, base + 8, base + 12,
               base + 16, base + 20, base + 24, base + 28);
        int r = tid >> 2, c0 = (tid & 3) * 32;
        *(v4f*)&sm->chol.Cs[r][c0]      = z0; *(v4f*)&sm->chol.Cs[r][c0 + 4]  = z1;
        *(v4f*)&sm->chol.Cs[r][c0 + 8]  = z2; *(v4f*)&sm->chol.Cs[r][c0 + 12] = z3;
        *(v4f*)&sm->chol.Cs[r][c0 + 16] = z4; *(v4f*)&sm->chol.Cs[r][c0 + 20] = z5;
        *(v4f*)&sm->chol.Cs[r][c0 + 24] = z6; *(v4f*)&sm->chol.Cs[r][c0 + 28] = z7;
    }
    syncL();
    // issue RHS loads now; they stay in flight across the whole factor
    // (all in-factor barriers are lgkm-only)
    int c = tid & 63, h = tid >> 6;
    int j0 = bid * 64;
    float acc[16];
    {
        const float* pRHS = &RHS[(h * 16) * 1024 + j0 + c];
        issS8(acc[0], acc[1], acc[2], acc[3], acc[4], acc[5], acc[6], acc[7],
              pRHS, pRHS + 1024, pRHS + 2048, pRHS + 3072,
              pRHS + 4096, pRHS + 5120, pRHS + 6144, pRHS + 7168);
        issS8(acc[8], acc[9], acc[10], acc[11], acc[12], acc[13], acc[14], acc[15],
              pRHS + 8192, pRHS + 9216, pRHS + 10240, pRHS + 11264,
              pRHS + 12288, pRHS + 13312, pRHS + 14336, pRHS + 15360);
    }
    int lane = tid & 63;
    // factor with panel lookahead: wave 0 factors panel kb+1 while
    // waves 1-7 apply panel kb's trailing update to columns >= base+16
    if (tid < 64) chol_panel(sm, 0, lane);
    syncL();
    for (int kb = 0; kb < 7; ++kb) {
        int k0 = kb * 16, base = k0 + 16;
        const float* idp = sm->chol.inv_d[kb & 1];
        int hh = tid >> 6, cc = tid & 63;
        int rlo = hh * 16;
        // phase 1: update the next panel's 16 columns with panel kb
        if (cc < 16 && rlo + 16 > base) {
            int j1 = base + cc;
            float w1[16];
            #pragma unroll
            for (int u = 0; u < 16; ++u) w1[u] = sm->chol.Cs[j1][k0 + u] * idp[u];
            int istart = rlo > base ? rlo : base;
            for (int i = istart; i < rlo + 16; ++i) {
                float a1 = 0.f;
                #pragma unroll
                for (int u = 0; u < 16; ++u) a1 += sm->chol.Cs[i][k0 + u] * w1[u];
                sm->chol.Cs[i][j1] -= a1;
            }
        }
        syncL();
        // phase 2: wave0 factors panel kb+1 || waves 1-7 update cols [base+16,128)
        if (tid < 64) {
            chol_panel(sm, kb + 1, lane);
        } else if (rlo + 16 > base) {
            int b2 = base + 16;
            int j1 = b2 + cc, j2 = b2 + cc + 64;
            bool has1 = j1 < 128, has2 = j2 < 128;
            if (has1) {
                float w1[16], w2[16];
                #pragma unroll
                for (int u = 0; u < 16; ++u) w1[u] = sm->chol.Cs[j1][k0 + u] * idp[u];
                if (has2) {
                    #pragma unroll
                    for (int u = 0; u < 16; ++u) w2[u] = sm->chol.Cs[j2][k0 + u] * idp[u];
                }
                int istart = rlo > base ? rlo : base;
                for (int i = istart; i < rlo + 16; ++i) {
                    float a1 = 0.f, a2 = 0.f;
                    #pragma unroll
                    for (int u = 0; u < 16; ++u) {
                        float v = sm->chol.Cs[i][k0 + u];
                        a1 += v * w1[u]; a2 += v * w2[u];
                    }
                    sm->chol.Cs[i][j1] -= a1;
                    if (has2) sm->chol.Cs[i][j2] -= a2;
                }
            }
        }
        syncL();
    }
    if (tid < 128) sm->chol.irs[tid] = __builtin_amdgcn_rsqf(sm->chol.Cs[tid][tid]);
    wtA16(acc);   // RHS loads have long completed; ties regs for the solve
    syncL();
    // forward solve: 8 bands of 16 rows, 64 columns per block
    for (int pb = 0; pb < 8; ++pb) {
        int p0 = pb * 16;
        if (h == pb) {
            #pragma unroll
            for (int kk = 0; kk < 16; ++kk) {
                int k = p0 + kk;
                float irsk = sm->chol.irs[k];
                float x = acc[kk] * irsk;
                acc[kk] = x;
                sm->chol.Xs[kk][c] = x;
                float xs = x * irsk;
                #pragma unroll
                for (int r = kk + 1; r < 16; ++r)
                    acc[r] -= sm->chol.Cs[p0 + r][k] * xs;
            }
        }
        syncL();
        if (h > pb) {
            int rb = h * 16;
            #pragma unroll
            for (int kk = 0; kk < 16; ++kk) {
                int k = p0 + kk;
                float xs = sm->chol.Xs[kk][c] * sm->chol.irs[k];
                #pragma unroll
                for (int r = 0; r < 16; ++r)
                    acc[r] -= sm->chol.Cs[rb + r][k] * xs;
            }
        }
        syncL();
    }
    #pragma unroll
    for (int r = 0; r < 16; ++r)
        ast(&Qt[(h * 16 + r) * 1024 + j0 + c], acc[r]);
}

#define GG_BODY(CK, RA, RB, WT) do { \
    WT; \
    *(v4f*)&sm->gg.As[(CK) & 1][r0][c4] = RA; \
    *(v4f*)&sm->gg.Bs[(CK) & 1][r0][c4] = RB; \
    syncL(); \
    for (int k = 0; k < 32; ++k) { \
        float2 a2 = *(const float2*)&sm->gg.As[(CK) & 1][k][ty * 2]; \
        float4 b4 = *(const float4*)&sm->gg.Bs[(CK) & 1][k][tx * 4]; \
        acc[0][0] += a2.x * b4.x; acc[0][1] += a2.x * b4.y; \
        acc[0][2] += a2.x * b4.z; acc[0][3] += a2.x * b4.w; \
        acc[1][0] += a2.y * b4.x; acc[1][1] += a2.y * b4.y; \
        acc[1][2] += a2.y * b4.z; acc[1][3] += a2.y * b4.w; \
    } \
} while (0)

// G = 8*Qt^T Qt + per-block row abs-sum partials; depth-4 pipeline.
__device__ __forceinline__ void dev_gemmG(Smem* sm, const float* Qt, float* G,
                                          float* Rpart, int bid) {
    int tid = threadIdx.x;
    int tx = tid & 15, ty = tid >> 4;
    int bx = bid & 15, by = bid >> 4;
    int a0 = by * 64, b0 = bx * 64;
    int r0 = tid >> 4, c4 = (tid & 15) << 2;
    float acc[2][4] = {};
    v4f a0r, b0r, a1r, b1r, a2r, b2r, a3r, b3r;
    const float* pa = &Qt[r0 * 1024 + a0 + c4];
    const float* pb = &Qt[r0 * 1024 + b0 + c4];
    iss2(a0r, b0r, pa, pb);
    iss2(a1r, b1r, pa + 32 * 1024, pb + 32 * 1024);
    iss2(a2r, b2r, pa + 64 * 1024, pb + 64 * 1024);
    iss2(a3r, b3r, pa + 96 * 1024, pb + 96 * 1024);
    GG_BODY(0, a0r, b0r, wt2_6(a0r, b0r));
    GG_BODY(1, a1r, b1r, wt2_4(a1r, b1r));
    GG_BODY(2, a2r, b2r, wt2_2(a2r, b2r));
    GG_BODY(3, a3r, b3r, wt2_0(a3r, b3r));
    float rsum[2] = {0.f, 0.f};
    #pragma unroll
    for (int i = 0; i < 2; ++i) {
        int aa = a0 + ty * 2 + i;
        float g[4];
        #pragma unroll
        for (int j = 0; j < 4; ++j) g[j] = 8.f * acc[i][j];
        float* gp = &G[aa * 1024 + b0 + tx * 4];
        ast2(gp, g[0], g[1]);
        ast2(gp + 2, g[2], g[3]);
        int bb = b0 + tx * 4;
        #pragma unroll
        for (int j = 0; j < 4; ++j) rsum[i] += (aa == bb + j) ? 0.f : fabsf(g[j]);
    }
    sm->gg.Rs[ty * 2 + 0][tx] = rsum[0];
    sm->gg.Rs[ty * 2 + 1][tx] = rsum[1];
    syncL();
    if (tid < 64) {
        float s = 0.f;
        #pragma unroll
        for (int x = 0; x < 16; ++x) s += sm->gg.Rs[tid][x];
        ast(&Rpart[(a0 + tid) * 16 + bx], s);
    }
}

// Ri[1024] into sm->gy.Ri; returns rth/delta (all threads); wave-shuffle reduce.
__device__ __forceinline__ void dev_ri(Smem* sm, const float* Rpart,
                                       float* rth, float* delta) {
    int tid = threadIdx.x;
    int e0 = tid, e1 = tid + 512;
    v4f t0, t1, t2, t3, u0, u1, u2, u3;
    cld4_8(t0, t1, t2, t3, u0, u1, u2, u3,
           &Rpart[e0 * 16], &Rpart[e0 * 16 + 4],
           &Rpart[e0 * 16 + 8], &Rpart[e0 * 16 + 12],
           &Rpart[e1 * 16], &Rpart[e1 * 16 + 4],
           &Rpart[e1 * 16 + 8], &Rpart[e1 * 16 + 12]);
    float s0 = 0.f;
    s0 += t0.x; s0 += t0.y; s0 += t0.z; s0 += t0.w;
    s0 += t1.x; s0 += t1.y; s0 += t1.z; s0 += t1.w;
    s0 += t2.x; s0 += t2.y; s0 += t2.z; s0 += t2.w;
    s0 += t3.x; s0 += t3.y; s0 += t3.z; s0 += t3.w;
    float s1 = 0.f;
    s1 += u0.x; s1 += u0.y; s1 += u0.z; s1 += u0.w;
    s1 += u1.x; s1 += u1.y; s1 += u1.z; s1 += u1.w;
    s1 += u2.x; s1 += u2.y; s1 += u2.z; s1 += u2.w;
    s1 += u3.x; s1 += u3.y; s1 += u3.z; s1 += u3.w;
    sm->gy.Ri[e0] = s0;
    sm->gy.Ri[e1] = s1;
    float mn = fminf(s0, s1);
    #pragma unroll
    for (int off = 32; off > 0; off >>= 1)
        mn = fminf(mn, __shfl_xor(mn, off));
    if ((tid & 63) == 0) sm->gy.red[tid >> 6] = mn;
    syncL();
    float r = sm->gy.red[0];
    #pragma unroll
    for (int w = 1; w < 8; ++w) r = fminf(r, sm->gy.red[w]);
    *rth = r;
    *delta = r / 1023.f;
}

#define GY_BODY(CK, RQ, RG, WT, REISSUE) do { \
    WT; \
    *(v2f*)&sm->gy.As[(CK) & 1][mA][k2] = RQ; \
    { \
        int aIdx = kc0 + (CK) * 32 + rg; \
        float ria = sm->gy.Ri[aIdx]; \
        v4f bw; \
        _Pragma("unroll") \
        for (int u = 0; u < 4; ++u) { \
            int bIdx = j0 + cg + u; \
            float g = RG[u]; \
            float sg = delta * ((g > 0.f) ? 1.f : ((g < 0.f) ? -1.f : 0.f)); \
            float ga = (ria > rth) ? sg : g; \
            float gb = (sm->gy.Ri[bIdx] > rth) ? sg : g; \
            bw[u] = (aIdx == bIdx) ? g : 0.5f * (ga + gb); \
        } \
        *(v4f*)&sm->gy.Bs[(CK) & 1][rg][cg] = bw; \
    } \
    syncL(); \
    REISSUE; \
    _Pragma("unroll") \
    for (int kb = 0; kb < 8; ++kb) { \
        v4f qa = *(const v4f*)&sm->gy.As[(CK) & 1][ty][kb * 4]; \
        _Pragma("unroll") \
        for (int kk = 0; kk < 4; ++kk) { \
            float4 b4 = *(const float4*)&sm->gy.Bs[(CK) & 1][kb * 4 + kk][tx * 4]; \
            float av = qa[kk]; \
            acc[0] += av * b4.x; acc[1] += av * b4.y; \
            acc[2] += av * b4.z; acc[3] += av * b4.w; \
        } \
    } \
} while (0)

// Y += Qt * G' over K-chunk kz (256 wide, atomicAdd); mask fused; depth-4 pipeline.
__device__ __forceinline__ void dev_gemmY(Smem* sm, const float* Qt, const float* G,
                                          float rth, float delta, float* Y, int bid) {
    int tid = threadIdx.x;
    int j0 = (bid & 15) * 64;
    int m0 = ((bid >> 4) & 3) * 32;
    int kz = bid >> 6;
    int kc0 = kz * 256;
    int tx = tid & 15, ty = tid >> 4;              // output: row m0+ty, 4 cols
    int mA = tid >> 4, k2 = (tid & 15) << 1;       // A staging: 2 floats/thread
    int rg = tid >> 4, cg = (tid & 15) << 2;       // B staging: 1 row, 4 cols
    float acc[4] = {};
    v2f q0r, q1r, q2r, q3r;
    v4f g0r, g1r, g2r, g3r;
    const float* pq = &Qt[(m0 + mA) * 1024 + kc0 + k2];
    const float* pg = &G[(kc0 + rg) * 1024 + j0 + cg];
    issY(q0r, g0r, pq, pg);
    issY(q1r, g1r, pq + 32, pg + 32 * 1024);
    issY(q2r, g2r, pq + 64, pg + 64 * 1024);
    issY(q3r, g3r, pq + 96, pg + 96 * 1024);
    GY_BODY(0, q0r, g0r, wtY_6(q0r, g0r), issY(q0r, g0r, pq + 128, pg + 128 * 1024));
    GY_BODY(1, q1r, g1r, wtY_6(q1r, g1r), issY(q1r, g1r, pq + 160, pg + 160 * 1024));
    GY_BODY(2, q2r, g2r, wtY_6(q2r, g2r), issY(q2r, g2r, pq + 192, pg + 192 * 1024));
    GY_BODY(3, q3r, g3r, wtY_6(q3r, g3r), issY(q3r, g3r, pq + 224, pg + 224 * 1024));
    GY_BODY(4, q0r, g0r, wtY_6(q0r, g0r), (void)0);
    GY_BODY(5, q1r, g1r, wtY_4(q1r, g1r), (void)0);
    GY_BODY(6, q2r, g2r, wtY_2(q2r, g2r), (void)0);
    GY_BODY(7, q3r, g3r, wtY_0(q3r, g3r), (void)0);
    #pragma unroll
    for (int j = 0; j < 4; ++j)
        atomicAdd(&Y[(m0 + ty) * 1024 + j0 + tx * 4 + j], acc[j]);
}

// trB partial: S-tile = (Qt^T Qt)[64x64]; s += sum G'(G_old)⊙S ; atomicAdd
__device__ __forceinline__ void dev_trB(Smem* sm, const float* Qt, const float* G,
                                        const float* Rpart, float* accb, int bid) {
    int tid = threadIdx.x;
    float rth, delta;
    dev_ri(sm, Rpart, &rth, &delta);
    __syncthreads();
    int tx = tid & 15, ty = tid >> 4;
    int a0 = (bid >> 4) * 64, b0 = (bid & 15) * 64;
    int r0 = tid >> 4, c4 = (tid & 15) << 2;
    float acc[2][4] = {};
    for (int kc = 0; kc < 128; kc += 32) {
        v4f av, bv;
        cld4_2(av, bv, &Qt[(kc + r0) * 1024 + a0 + c4],
               &Qt[(kc + r0) * 1024 + b0 + c4]);
        *(v4f*)&sm->tb.As[r0][c4] = av;
        *(v4f*)&sm->tb.Bs[r0][c4] = bv;
        __syncthreads();
        for (int k = 0; k < 32; ++k) {
            float2 a2 = *(const float2*)&sm->tb.As[k][ty * 2];
            float4 b4 = *(const float4*)&sm->tb.Bs[k][tx * 4];
            acc[0][0] += a2.x * b4.x; acc[0][1] += a2.x * b4.y;
            acc[0][2] += a2.x * b4.z; acc[0][3] += a2.x * b4.w;
            acc[1][0] += a2.y * b4.x; acc[1][1] += a2.y * b4.y;
            acc[1][2] += a2.y * b4.z; acc[1][3] += a2.y * b4.w;
        }
        __syncthreads();
    }
    float rib[4];
    #pragma unroll
    for (int j = 0; j < 4; ++j) {
        int bb = b0 + tx * 4 + j;
        v4f t0, t1, t2, t3;
        cld4_4(t0, t1, t2, t3, &Rpart[bb * 16], &Rpart[bb * 16 + 4],
               &Rpart[bb * 16 + 8], &Rpart[bb * 16 + 12]);
        float s = 0.f;
        s += t0.x; s += t0.y; s += t0.z; s += t0.w;
        s += t1.x; s += t1.y; s += t1.z; s += t1.w;
        s += t2.x; s += t2.y; s += t2.z; s += t2.w;
        s += t3.x; s += t3.y; s += t3.z; s += t3.w;
        rib[j] = s;
    }
    float s = 0.f;
    #pragma unroll
    for (int i = 0; i < 2; ++i) {
        int aa = a0 + ty * 2 + i;
        v4f t0, t1, t2, t3;
        cld4_4(t0, t1, t2, t3, &Rpart[aa * 16], &Rpart[aa * 16 + 4],
               &Rpart[aa * 16 + 8], &Rpart[aa * 16 + 12]);
        float ria = 0.f;
        ria += t0.x; ria += t0.y; ria += t0.z; ria += t0.w;
        ria += t1.x; ria += t1.y; ria += t1.z; ria += t1.w;
        ria += t2.x; ria += t2.y; ria += t2.z; ria += t2.w;
        ria += t3.x; ria += t3.y; ria += t3.z; ria += t3.w;
        float g0, g1, g2, g3;
        const float* gp = &G[aa * 1024 + b0 + tx * 4];
        cld1_4(g0, g1, g2, g3, gp, gp + 1, gp + 2, gp + 3);
        float gv[4] = {g0, g1, g2, g3};
        #pragma unroll
        for (int j = 0; j < 4; ++j) {
            int bb = b0 + tx * 4 + j;
            float g = gv[j];
            float sg = delta * ((g > 0.f) ? 1.f : ((g < 0.f) ? -1.f : 0.f));
            float ga = (ria > rth) ? sg : g;
            float gb = (rib[j] > rth) ? sg : g;
            float gp2 = (aa == bb) ? g : 0.5f * (ga + gb);
            s += gp2 * acc[i][j];
        }
    }
    __syncthreads();
    sm->tb.red[tid] = s;
    __syncthreads();
    for (int w = 256; w > 0; w >>= 1) {
        if (tid < w) sm->tb.red[tid] += sm->tb.red[tid + w];
        __syncthreads();
    }
    if (tid == 0) atomicAdd(&accb[2], sm->tb.red[0]);
}

__global__ __launch_bounds__(512) void mega(const float* __restrict__ t1,
                                            const float* __restrict__ t2,
                                            const float* __restrict__ params,
                                            const float* __restrict__ tmin,
                                            const float* __restrict__ tmax,
                                            const float* __restrict__ beta,
                                            const float* __restrict__ R,
                                            float* ws, float* out) {
    float* G     = ws + OFF_G;
    float* Qt    = ws + OFF_QT;
    float* Y     = ws + OFF_Y;
    float* C     = ws + OFF_C;
    float* Rpart = ws + OFF_RP;
    float* accb  = ws + OFF_ACC;
    unsigned* bb = (unsigned*)(ws + OFF_BAR);
    __shared__ Smem sm;
    int bid = blockIdx.x;
    int tid = threadIdx.x;
    unsigned phA = 0, phB = 0, phC = 0, phE = 0;

    // P0a: zero C (blocks 0-31); stats elsewhere
    if (bid < 32) {
        ast(&C[bid * 512 + tid], 0.f);
    } else if (bid < 250) dev_match(&sm, t1, t2, accb, bid - 32);
    else if (bid == 250) dev_range(&sm, params, tmin, tmax, accb);
    else if (bid < 255) dev_sumsq(&sm, R, accb, bid - 251);
    ++phC;
    if (bid < 32) {
        bar_arrive(bb, BAR_C + (bid >> 2));
        bar_wait(bb, BAR_C, 8, phC * 4);
        dev_syrk(&sm, R, R, C, bid);
    }
    ++phC;
    if (bid < 32) bar_arrive(bb, BAR_C + (bid >> 2));
    if (bid < 16) {
        bar_wait(bb, BAR_C, 8, phC * 4);
        dev_cholTrsm(&sm, C, R, Qt, bid);
    }
    ++phE;
    if (bid < 16) bar_arrive(bb, BAR_E + (bid >> 2));
    bar_wait(bb, BAR_E, 4, phE * 4);

    for (int it = 0; it < 50; ++it) {
        dev_gemmG(&sm, Qt, G, Rpart, bid);
        // zero Y (all blocks) and C (blocks 0-31) for this iteration's consumers
        ast(&Y[bid * 512 + tid], 0.f);
        if (bid < 32) ast(&C[bid * 512 + tid], 0.f);
        ++phA;
        bar_arrive(bb, BAR_A + (bid & 63));
        bar_wait(bb, BAR_A, 64, phA * 4);
        {
            float rth, delta;
            dev_ri(&sm, Rpart, &rth, &delta);
            dev_gemmY(&sm, Qt, G, rth, delta, Y, bid);
        }
        ++phB;
        bar_arrive(bb, BAR_B + (bid & 63));
        if (bid < 32) {
            bar_wait(bb, BAR_B, 64, phB * 4);
            dev_syrk(&sm, Y, Y, C, bid);
        }
        ++phC;
        if (bid < 32) bar_arrive(bb, BAR_C + (bid >> 2));
        if (bid < 16) {
            bar_wait(bb, BAR_C, 8, phC * 4);
            dev_cholTrsm(&sm, C, Y, Qt, bid);
        }
        ++phE;
        if (bid < 16) bar_arrive(bb, BAR_E + (bid >> 2));
        bar_wait(bb, BAR_E, 4, phE * 4);
    }

    dev_trB(&sm, Qt, G, Rpart, accb, bid);
    ++phA;
    bar_arrive(bb, BAR_A + (bid & 63));
    if (bid == 0) {
        bar_wait(bb, BAR_A, 64, phA * 4);
        if (tid == 0)
            out[0] = ald(&accb[0]) / 4194304.f + beta[0] * (ald(&accb[1]) / 2176.f)
                   + (ald(&accb[2]) + ald(&accb[3])) / 131072.f;
    }
}

extern "C" void kernel_launch(void* const* d_in, const int* in_sizes, int n_in,
                              void* d_out, int out_size, void* d_ws, size_t ws_size,
                              hipStream_t stream) {
    const float* t1 = (const float*)d_in[0];
    const float* t2 = (const float*)d_in[1];
    const float* params = (const float*)d_in[2];
    const float* tmin = (const float*)d_in[3];
    const float* tmax = (const float*)d_in[4];
    const float* beta = (const float*)d_in[5];
    const float* R = (const float*)d_in[6];
    float* ws = (float*)d_ws;
    float* out = (float*)d_out;

    // zero accumulators + barrier counter lines (144 lines * 64B + 64B acc)
    hipMemsetAsync(ws + OFF_ACC, 0, 9280, stream);
    mega<<<NBLK, NTHR, 0, stream>>>(t1, t2, params, tmin, tmax, beta, R, ws, out);
}

// Round 3
// 7202.283 us; speedup vs baseline: 3.7561x; 3.7561x over previous
//
#include <hip/hip_runtime.h>

#define NBLK 256
#define NTHR 512

// workspace layout (floats)
#define OFF_G    0            // 1024*1024
#define OFF_QT   1048576      // 128*1024
#define OFF_Y    1179648      // 128*1024 (atomic-accumulated)
#define OFF_C    1703936      // 128*128 (atomic-accumulated)
#define OFF_RP   1851392      // Rpart[1024][16]
#define OFF_ACC  1867776      // 4 floats
#define OFF_BAR  1867792      // 144 counter lines (stride 16 u32 = 64B)

#define BAR_A 0    // 64 lines, 256 arrive / 256 wait
#define BAR_B 64   // 64 lines, 256 arrive / 32 wait
#define BAR_C 128  // 8 lines, 32 arrive / {32,16} wait
#define BAR_E 136  // 4 lines, 16 arrive / 256 wait

typedef float v4f __attribute__((ext_vector_type(4)));

// ---- batched agent-coherent loads (sc1), wait included ----
__device__ __forceinline__ void cld4_8(v4f& a, v4f& b, v4f& c, v4f& d,
                                       v4f& e, v4f& f, v4f& g, v4f& h,
                                       const float* pa, const float* pb,
                                       const float* pc, const float* pd,
                                       const float* pe, const float* pf,
                                       const float* pg, const float* ph) {
    asm volatile("global_load_dwordx4 %0, %8, off sc1\n\t"
                 "global_load_dwordx4 %1, %9, off sc1\n\t"
                 "global_load_dwordx4 %2, %10, off sc1\n\t"
                 "global_load_dwordx4 %3, %11, off sc1\n\t"
                 "global_load_dwordx4 %4, %12, off sc1\n\t"
                 "global_load_dwordx4 %5, %13, off sc1\n\t"
                 "global_load_dwordx4 %6, %14, off sc1\n\t"
                 "global_load_dwordx4 %7, %15, off sc1\n\t"
                 "s_waitcnt vmcnt(0)"
                 : "=&v"(a), "=&v"(b), "=&v"(c), "=&v"(d),
                   "=&v"(e), "=&v"(f), "=&v"(g), "=&v"(h)
                 : "v"(pa), "v"(pb), "v"(pc), "v"(pd),
                   "v"(pe), "v"(pf), "v"(pg), "v"(ph) : "memory");
}
__device__ __forceinline__ void cld4_4(v4f& a, v4f& b, v4f& c, v4f& d,
                                       const float* pa, const float* pb,
                                       const float* pc, const float* pd) {
    asm volatile("global_load_dwordx4 %0, %4, off sc1\n\t"
                 "global_load_dwordx4 %1, %5, off sc1\n\t"
                 "global_load_dwordx4 %2, %6, off sc1\n\t"
                 "global_load_dwordx4 %3, %7, off sc1\n\t"
                 "s_waitcnt vmcnt(0)"
                 : "=&v"(a), "=&v"(b), "=&v"(c), "=&v"(d)
                 : "v"(pa), "v"(pb), "v"(pc), "v"(pd) : "memory");
}
__device__ __forceinline__ void cld4_2(v4f& a, v4f& b,
                                       const float* pa, const float* pb) {
    asm volatile("global_load_dwordx4 %0, %2, off sc1\n\t"
                 "global_load_dwordx4 %1, %3, off sc1\n\t"
                 "s_waitcnt vmcnt(0)"
                 : "=&v"(a), "=&v"(b) : "v"(pa), "v"(pb) : "memory");
}
__device__ __forceinline__ void cld1_4(float& a, float& b, float& c, float& d,
                                       const float* pa, const float* pb,
                                       const float* pc, const float* pd) {
    asm volatile("global_load_dword %0, %4, off sc1\n\t"
                 "global_load_dword %1, %5, off sc1\n\t"
                 "global_load_dword %2, %6, off sc1\n\t"
                 "global_load_dword %3, %7, off sc1\n\t"
                 "s_waitcnt vmcnt(0)"
                 : "=&v"(a), "=&v"(b), "=&v"(c), "=&v"(d)
                 : "v"(pa), "v"(pb), "v"(pc), "v"(pd) : "memory");
}
__device__ __forceinline__ void cld1_8(float& a, float& b, float& c, float& d,
                                       float& e, float& f, float& g, float& h,
                                       const float* pa, const float* pb,
                                       const float* pc, const float* pd,
                                       const float* pe, const float* pf,
                                       const float* pg, const float* ph) {
    asm volatile("global_load_dword %0, %8, off sc1\n\t"
                 "global_load_dword %1, %9, off sc1\n\t"
                 "global_load_dword %2, %10, off sc1\n\t"
                 "global_load_dword %3, %11, off sc1\n\t"
                 "global_load_dword %4, %12, off sc1\n\t"
                 "global_load_dword %5, %13, off sc1\n\t"
                 "global_load_dword %6, %14, off sc1\n\t"
                 "global_load_dword %7, %15, off sc1\n\t"
                 "s_waitcnt vmcnt(0)"
                 : "=&v"(a), "=&v"(b), "=&v"(c), "=&v"(d),
                   "=&v"(e), "=&v"(f), "=&v"(g), "=&v"(h)
                 : "v"(pa), "v"(pb), "v"(pc), "v"(pd),
                   "v"(pe), "v"(pf), "v"(pg), "v"(ph) : "memory");
}
// ---- issue-only variants + explicit waits (depth-1 prefetch) ----
__device__ __forceinline__ void iss2(v4f& a, v4f& b,
                                     const float* pa, const float* pb) {
    asm volatile("global_load_dwordx4 %0, %2, off sc1\n\t"
                 "global_load_dwordx4 %1, %3, off sc1"
                 : "=&v"(a), "=&v"(b) : "v"(pa), "v"(pb) : "memory");
}
__device__ __forceinline__ void wt2(v4f& a, v4f& b) {
    asm volatile("s_waitcnt vmcnt(0)"
                 : "+v"(a), "+v"(b) :: "memory");
}
__device__ __forceinline__ void iss1(v4f& a, const float* pa) {
    asm volatile("global_load_dwordx4 %0, %1, off sc1"
                 : "=&v"(a) : "v"(pa) : "memory");
}
__device__ __forceinline__ void wt1(v4f& a) {
    asm volatile("s_waitcnt vmcnt(0)" : "+v"(a) :: "memory");
}

// barrier that waits LDS ops only — in-flight global loads survive it
__device__ __forceinline__ void syncL() {
    asm volatile("s_waitcnt lgkmcnt(0)" ::: "memory");
    __builtin_amdgcn_s_barrier();
    asm volatile("" ::: "memory");
}

// ---- coherent scalar/pair stores + loads ----
__device__ __forceinline__ void ast2(float* p, float a, float b) {
    union { unsigned long long u; float f[2]; } c; c.f[0] = a; c.f[1] = b;
    __hip_atomic_store((unsigned long long*)p, c.u,
                       __ATOMIC_RELAXED, __HIP_MEMORY_SCOPE_AGENT);
}
__device__ __forceinline__ float ald(const float* p) {
    return __hip_atomic_load(p, __ATOMIC_RELAXED, __HIP_MEMORY_SCOPE_AGENT);
}
__device__ __forceinline__ void ast(float* p, float x) {
    __hip_atomic_store(p, x, __ATOMIC_RELAXED, __HIP_MEMORY_SCOPE_AGENT);
}

__device__ __forceinline__ void bar_arrive(unsigned* bb, int line) {
    __syncthreads();
    if (threadIdx.x == 0)
        __hip_atomic_fetch_add(bb + line * 16, 1u,
                               __ATOMIC_RELAXED, __HIP_MEMORY_SCOPE_AGENT);
}
__device__ __forceinline__ void bar_wait(unsigned* bb, int wbase, int nlines,
                                         unsigned tgt) {
    if ((int)threadIdx.x < nlines) {
        while (__hip_atomic_load(bb + (wbase + threadIdx.x) * 16,
                                 __ATOMIC_RELAXED, __HIP_MEMORY_SCOPE_AGENT) < tgt)
            __builtin_amdgcn_s_sleep(1);
    }
    __builtin_amdgcn_s_waitcnt(0);
    __syncthreads();
}

union Smem {
    struct { float As[32][68]; float Bs[32][68]; float Rs[64][17]; } gg;   // gemmG + syrk
    struct { float Cs[128][129]; float inv_d[16]; float irs[128];
             float Xs[16][64]; } chol;                                     // 70720 B
    struct { float Ri[1024]; float red[512]; float As[32][36]; float Bs[32][68]; } gy;
    struct { float As[32][68]; float Bs[32][68]; float red[512]; } tb;
    float red[512];
};

__device__ __forceinline__ void dev_match(Smem* sm, const float* t1, const float* t2,
                                          float* accb, int w) {
    int tid = threadIdx.x;
    const float4* a = (const float4*)t1;
    const float4* b = (const float4*)t2;
    float s = 0.f;
    for (int i = w * 512 + tid; i < 1048576; i += 218 * 512) {
        float4 x = a[i], y = b[i];
        float d0 = x.x - y.x, d1 = x.y - y.y, d2 = x.z - y.z, d3 = x.w - y.w;
        s += d0 * d0 + d1 * d1 + d2 * d2 + d3 * d3;
    }
    sm->red[tid] = s; __syncthreads();
    for (int w2 = 256; w2 > 0; w2 >>= 1) {
        if (tid < w2) sm->red[tid] += sm->red[tid + w2];
        __syncthreads();
    }
    if (tid == 0) atomicAdd(&accb[0], sm->red[0]);
    __syncthreads();
}

__device__ __forceinline__ void dev_range(Smem* sm, const float* params, const float* tmin,
                                          const float* tmax, float* accb) {
    int tid = threadIdx.x;
    float a = tmin[0], b = tmax[0];
    const float d = 0.01f;
    float s = 0.f;
    for (int i = tid; i < 128 * 17; i += 512) {
        float p = params[i];
        float r1 = (p - a - d) / (-d);
        float r2 = (p - b + d) / d;
        s += fmaxf(fmaxf(r1, r2), 0.f);
    }
    sm->red[tid] = s; __syncthreads();
    for (int w = 256; w > 0; w >>= 1) {
        if (tid < w) sm->red[tid] += sm->red[tid + w];
        __syncthreads();
    }
    if (tid == 0) atomicAdd(&accb[1], sm->red[0]);
    __syncthreads();
}

__device__ __forceinline__ void dev_sumsq(Smem* sm, const float* X, float* accb, int w) {
    int tid = threadIdx.x;
    float s = 0.f;
    for (int i = w * 512 + tid; i < 131072; i += 2048) { float v = X[i]; s += v * v; }
    sm->red[tid] = s; __syncthreads();
    for (int w2 = 256; w2 > 0; w2 >>= 1) {
        if (tid < w2) sm->red[tid] += sm->red[tid + w2];
        __syncthreads();
    }
    if (tid == 0) atomicAdd(&accb[3], sm->red[0]);
    __syncthreads();
}

// C += A-tile(64 rows p0) x B-tile(64 rows q0) over K-chunk z of 128 (atomicAdd).
// Depth-1 prefetch that survives the lgkm-only barriers.
__device__ __forceinline__ void dev_syrk(Smem* sm, const float* A, const float* B,
                                         float* C, int bid) {
    int tid = threadIdx.x;
    int q0 = (bid & 1) * 64, p0 = ((bid >> 1) & 1) * 64, z = bid >> 2;
    int kc0 = z * 128;
    int p = tid & 63, kg = (tid >> 6) * 4;
    int tx = tid & 15, ty = tid >> 4;
    float acc[2][4] = {};
    v4f av, bv;
    iss2(av, bv, &A[(p0 + p) * 1024 + kc0 + kg], &B[(q0 + p) * 1024 + kc0 + kg]);
    for (int ck = 0; ck < 4; ++ck) {
        wt2(av, bv);
        sm->gg.As[kg + 0][p] = av.x; sm->gg.As[kg + 1][p] = av.y;
        sm->gg.As[kg + 2][p] = av.z; sm->gg.As[kg + 3][p] = av.w;
        sm->gg.Bs[kg + 0][p] = bv.x; sm->gg.Bs[kg + 1][p] = bv.y;
        sm->gg.Bs[kg + 2][p] = bv.z; sm->gg.Bs[kg + 3][p] = bv.w;
        syncL();
        if (ck < 3) {
            int kn = kc0 + (ck + 1) * 32 + kg;
            iss2(av, bv, &A[(p0 + p) * 1024 + kn], &B[(q0 + p) * 1024 + kn]);
        }
        for (int k = 0; k < 32; ++k) {
            float2 a2 = *(const float2*)&sm->gg.As[k][ty * 2];
            float4 b4 = *(const float4*)&sm->gg.Bs[k][tx * 4];
            acc[0][0] += a2.x * b4.x; acc[0][1] += a2.x * b4.y;
            acc[0][2] += a2.x * b4.z; acc[0][3] += a2.x * b4.w;
            acc[1][0] += a2.y * b4.x; acc[1][1] += a2.y * b4.y;
            acc[1][2] += a2.y * b4.z; acc[1][3] += a2.y * b4.w;
        }
        syncL();
    }
    #pragma unroll
    for (int i = 0; i < 2; ++i)
        #pragma unroll
        for (int j = 0; j < 4; ++j)
            atomicAdd(&C[(p0 + ty * 2 + i) * 128 + q0 + tx * 4 + j], acc[i][j]);
}

// Fused: redundant Cholesky of C (16 blocks) + forward solve for 64 columns each.
__device__ __forceinline__ void dev_cholTrsm(Smem* sm, const float* C, const float* RHS,
                                             float* Qt, int bid) {
    int tid = threadIdx.x;
    // stage C (32 floats/thread, one batch)
    {
        const float* base = C + tid * 32;
        v4f z0, z1, z2, z3, z4, z5, z6, z7;
        cld4_8(z0, z1, z2, z3, z4, z5, z6, z7,
               base, base + 4, base + 8, base + 12,
               base + 16, base + 20, base + 24, base + 28);
        int r = tid >> 2, c0 = (tid & 3) * 32;
        *(v4f*)&sm->chol.Cs[r][c0]      = z0; *(v4f*)&sm->chol.Cs[r][c0 + 4]  = z1;
        *(v4f*)&sm->chol.Cs[r][c0 + 8]  = z2; *(v4f*)&sm->chol.Cs[r][c0 + 12] = z3;
        *(v4f*)&sm->chol.Cs[r][c0 + 16] = z4; *(v4f*)&sm->chol.Cs[r][c0 + 20] = z5;
        *(v4f*)&sm->chol.Cs[r][c0 + 24] = z6; *(v4f*)&sm->chol.Cs[r][c0 + 28] = z7;
    }
    __syncthreads();
    int lane = tid & 63;
    for (int kb = 0; kb < 8; ++kb) {
        int k0 = kb * 16;
        if (tid < 64) {
            float P0[16], P1[16], invs[16];
            #pragma unroll
            for (int u = 0; u < 16; ++u) {
                P0[u] = sm->chol.Cs[lane][k0 + u];
                P1[u] = sm->chol.Cs[lane + 64][k0 + u];
            }
            #pragma unroll
            for (int kk = 0; kk < 16; ++kk) {
                int k = k0 + kk;
                int src = k & 63;
                bool hi = (k >= 64);
                float pr[16];
                #pragma unroll
                for (int u = 0; u < 16; ++u)
                    if (u >= kk) pr[u] = __shfl(hi ? P1[u] : P0[u], src);
                float inv = __builtin_amdgcn_rcpf(pr[kk]);
                invs[kk] = inv;
                float f0 = (lane > k) ? P0[kk] * inv : 0.f;
                float f1 = ((lane + 64) > k) ? P1[kk] * inv : 0.f;
                #pragma unroll
                for (int u = kk + 1; u < 16; ++u) {
                    P0[u] -= f0 * pr[u];
                    P1[u] -= f1 * pr[u];
                }
            }
            #pragma unroll
            for (int u = 0; u < 16; ++u) {
                sm->chol.Cs[lane][k0 + u] = P0[u];
                sm->chol.Cs[lane + 64][k0 + u] = P1[u];
            }
            if (lane == 0) {
                #pragma unroll
                for (int kk = 0; kk < 16; ++kk) sm->chol.inv_d[kk] = invs[kk];
            }
        }
        __syncthreads();
        int base = k0 + 16;
        if (base < 128) {
            int hh = tid >> 6, cc = tid & 63;
            int j1 = base + cc;
            int j2 = base + cc + 64;
            bool has1 = (j1 < 128), has2 = (j2 < 128);
            float w1[16], w2[16];
            if (has1) {
                #pragma unroll
                for (int u = 0; u < 16; ++u) w1[u] = sm->chol.Cs[j1][k0 + u] * sm->chol.inv_d[u];
            }
            if (has2) {
                #pragma unroll
                for (int u = 0; u < 16; ++u) w2[u] = sm->chol.Cs[j2][k0 + u] * sm->chol.inv_d[u];
            }
            int rlo = hh * 16;
            int istart = rlo > base ? rlo : base;
            for (int i = istart; i < rlo + 16; ++i) {
                float v[16];
                #pragma unroll
                for (int u = 0; u < 16; ++u) v[u] = sm->chol.Cs[i][k0 + u];
                float a1 = 0.f, a2 = 0.f;
                #pragma unroll
                for (int u = 0; u < 16; ++u) { a1 += v[u] * w1[u]; a2 += v[u] * w2[u]; }
                if (has1) sm->chol.Cs[i][j1] -= a1;
                if (has2) sm->chol.Cs[i][j2] -= a2;
            }
        }
        __syncthreads();
    }
    if (tid < 128) sm->chol.irs[tid] = __builtin_amdgcn_rsqf(sm->chol.Cs[tid][tid]);
    // RHS: 8 bands of 16 rows, 64 columns per block
    int c = tid & 63, h = tid >> 6;
    int j0 = bid * 64;
    float acc[16];
    {
        const float* p = &RHS[(h * 16) * 1024 + j0 + c];
        cld1_8(acc[0], acc[1], acc[2], acc[3], acc[4], acc[5], acc[6], acc[7],
               p, p + 1024, p + 2048, p + 3072, p + 4096, p + 5120, p + 6144, p + 7168);
        cld1_8(acc[8], acc[9], acc[10], acc[11], acc[12], acc[13], acc[14], acc[15],
               p + 8192, p + 9216, p + 10240, p + 11264,
               p + 12288, p + 13312, p + 14336, p + 15360);
    }
    __syncthreads();
    for (int pb = 0; pb < 8; ++pb) {
        int p0 = pb * 16;
        if (h == pb) {
            #pragma unroll
            for (int kk = 0; kk < 16; ++kk) {
                int k = p0 + kk;
                float irsk = sm->chol.irs[k];
                float x = acc[kk] * irsk;
                acc[kk] = x;
                sm->chol.Xs[kk][c] = x;
                float xs = x * irsk;
                #pragma unroll
                for (int r = kk + 1; r < 16; ++r)
                    acc[r] -= sm->chol.Cs[p0 + r][k] * xs;
            }
        }
        __syncthreads();
        if (h > pb) {
            int rb = h * 16;
            #pragma unroll
            for (int kk = 0; kk < 16; ++kk) {
                int k = p0 + kk;
                float xs = sm->chol.Xs[kk][c] * sm->chol.irs[k];
                #pragma unroll
                for (int r = 0; r < 16; ++r)
                    acc[r] -= sm->chol.Cs[rb + r][k] * xs;
            }
        }
        __syncthreads();
    }
    #pragma unroll
    for (int r = 0; r < 16; ++r)
        ast(&Qt[(h * 16 + r) * 1024 + j0 + c], acc[r]);
}

// G = 8*Qt^T Qt + per-block row abs-sum partials (Rpart[row][16]); prefetched.
__device__ __forceinline__ void dev_gemmG(Smem* sm, const float* Qt, float* G,
                                          float* Rpart, int bid) {
    int tid = threadIdx.x;
    int tx = tid & 15, ty = tid >> 4;             // ty 0..31 -> 2 rows
    int bx = bid & 15, by = bid >> 4;
    int a0 = by * 64, b0 = bx * 64;
    int r0 = tid >> 4, c4 = (tid & 15) << 2;      // staging: k-row, 4 cols
    float acc[2][4] = {};
    v4f av, bv;
    iss2(av, bv, &Qt[r0 * 1024 + a0 + c4], &Qt[r0 * 1024 + b0 + c4]);
    for (int kc = 0; kc < 128; kc += 32) {
        wt2(av, bv);
        *(v4f*)&sm->gg.As[r0][c4] = av;
        *(v4f*)&sm->gg.Bs[r0][c4] = bv;
        syncL();
        if (kc < 96) {
            int kn = kc + 32;
            iss2(av, bv, &Qt[(kn + r0) * 1024 + a0 + c4],
                 &Qt[(kn + r0) * 1024 + b0 + c4]);
        }
        for (int k = 0; k < 32; ++k) {
            float2 a2 = *(const float2*)&sm->gg.As[k][ty * 2];
            float4 b4 = *(const float4*)&sm->gg.Bs[k][tx * 4];
            acc[0][0] += a2.x * b4.x; acc[0][1] += a2.x * b4.y;
            acc[0][2] += a2.x * b4.z; acc[0][3] += a2.x * b4.w;
            acc[1][0] += a2.y * b4.x; acc[1][1] += a2.y * b4.y;
            acc[1][2] += a2.y * b4.z; acc[1][3] += a2.y * b4.w;
        }
        syncL();
    }
    float rsum[2] = {0.f, 0.f};
    #pragma unroll
    for (int i = 0; i < 2; ++i) {
        int aa = a0 + ty * 2 + i;
        float g[4];
        #pragma unroll
        for (int j = 0; j < 4; ++j) g[j] = 8.f * acc[i][j];
        float* gp = &G[aa * 1024 + b0 + tx * 4];
        ast2(gp, g[0], g[1]);
        ast2(gp + 2, g[2], g[3]);
        int bb = b0 + tx * 4;
        #pragma unroll
        for (int j = 0; j < 4; ++j) rsum[i] += (aa == bb + j) ? 0.f : fabsf(g[j]);
    }
    sm->gg.Rs[ty * 2 + 0][tx] = rsum[0];
    sm->gg.Rs[ty * 2 + 1][tx] = rsum[1];
    __syncthreads();
    if (tid < 64) {
        float s = 0.f;
        #pragma unroll
        for (int x = 0; x < 16; ++x) s += sm->gg.Rs[tid][x];
        ast(&Rpart[(a0 + tid) * 16 + bx], s);
    }
}

// Ri[1024] into sm->gy.Ri; returns rth/delta (all threads); wave-shuffle reduce.
__device__ __forceinline__ void dev_ri(Smem* sm, const float* Rpart,
                                       float* rth, float* delta) {
    int tid = threadIdx.x;
    int e0 = tid, e1 = tid + 512;
    v4f t0, t1, t2, t3, u0, u1, u2, u3;
    cld4_8(t0, t1, t2, t3, u0, u1, u2, u3,
           &Rpart[e0 * 16], &Rpart[e0 * 16 + 4],
           &Rpart[e0 * 16 + 8], &Rpart[e0 * 16 + 12],
           &Rpart[e1 * 16], &Rpart[e1 * 16 + 4],
           &Rpart[e1 * 16 + 8], &Rpart[e1 * 16 + 12]);
    float s0 = 0.f;
    s0 += t0.x; s0 += t0.y; s0 += t0.z; s0 += t0.w;
    s0 += t1.x; s0 += t1.y; s0 += t1.z; s0 += t1.w;
    s0 += t2.x; s0 += t2.y; s0 += t2.z; s0 += t2.w;
    s0 += t3.x; s0 += t3.y; s0 += t3.z; s0 += t3.w;
    float s1 = 0.f;
    s1 += u0.x; s1 += u0.y; s1 += u0.z; s1 += u0.w;
    s1 += u1.x; s1 += u1.y; s1 += u1.z; s1 += u1.w;
    s1 += u2.x; s1 += u2.y; s1 += u2.z; s1 += u2.w;
    s1 += u3.x; s1 += u3.y; s1 += u3.z; s1 += u3.w;
    sm->gy.Ri[e0] = s0;
    sm->gy.Ri[e1] = s1;
    float mn = fminf(s0, s1);
    #pragma unroll
    for (int off = 32; off > 0; off >>= 1)
        mn = fminf(mn, __shfl_xor(mn, off));
    if ((tid & 63) == 0) sm->gy.red[tid >> 6] = mn;
    __syncthreads();
    float r = sm->gy.red[0];
    #pragma unroll
    for (int w = 1; w < 8; ++w) r = fminf(r, sm->gy.red[w]);
    *rth = r;
    *delta = r / 1023.f;
}

// Y += Qt * G' over K-chunk kz (256 wide, atomicAdd); mask fused; prefetched.
__device__ __forceinline__ void dev_gemmY(Smem* sm, const float* Qt, const float* G,
                                          float rth, float delta, float* Y, int bid) {
    int tid = threadIdx.x;
    int j0 = (bid & 15) * 64;
    int m0 = ((bid >> 4) & 3) * 32;
    int kz = bid >> 6;
    int kc0 = kz * 256;
    int tx = tid & 15, ty = tid >> 4;              // output: row m0+ty, 4 cols
    int m = (tid & 255) >> 3, k4 = (tid & 7) << 2; // A staging (tid<256)
    int rg = tid >> 4, cg = (tid & 15) << 2;       // B staging: 1 row, 4 cols
    float acc[4] = {};
    v4f q, g0;
    if (tid < 256) iss1(q, &Qt[(m0 + m) * 1024 + kc0 + k4]);
    iss1(g0, &G[(kc0 + rg) * 1024 + j0 + cg]);
    for (int kc = kc0; kc < kc0 + 256; kc += 32) {
        wt1(g0);
        if (tid < 256) {
            wt1(q);
            *(v4f*)&sm->gy.As[m][k4] = q;          // [m][k] layout, vector store
        }
        {
            int a = kc + rg;
            float ria = sm->gy.Ri[a];
            v4f bw;
            #pragma unroll
            for (int u = 0; u < 4; ++u) {
                int b = j0 + cg + u;
                float g = g0[u];
                float sg = delta * ((g > 0.f) ? 1.f : ((g < 0.f) ? -1.f : 0.f));
                float ga = (ria > rth) ? sg : g;
                float gb = (sm->gy.Ri[b] > rth) ? sg : g;
                bw[u] = (a == b) ? g : 0.5f * (ga + gb);
            }
            *(v4f*)&sm->gy.Bs[rg][cg] = bw;        // vector store
        }
        syncL();
        if (kc < kc0 + 224) {
            int kn = kc + 32;
            if (tid < 256) iss1(q, &Qt[(m0 + m) * 1024 + kn + k4]);
            iss1(g0, &G[(kn + rg) * 1024 + j0 + cg]);
        }
        #pragma unroll
        for (int kb = 0; kb < 8; ++kb) {
            v4f qa = *(const v4f*)&sm->gy.As[ty][kb * 4];
            #pragma unroll
            for (int kk = 0; kk < 4; ++kk) {
                float4 b4 = *(const float4*)&sm->gy.Bs[kb * 4 + kk][tx * 4];
                float a = qa[kk];
                acc[0] += a * b4.x; acc[1] += a * b4.y;
                acc[2] += a * b4.z; acc[3] += a * b4.w;
            }
        }
        syncL();
    }
    #pragma unroll
    for (int j = 0; j < 4; ++j)
        atomicAdd(&Y[(m0 + ty) * 1024 + j0 + tx * 4 + j], acc[j]);
}

// trB partial: S-tile = (Qt^T Qt)[64x64]; s += sum G'(G_old)⊙S ; atomicAdd
__device__ __forceinline__ void dev_trB(Smem* sm, const float* Qt, const float* G,
                                        const float* Rpart, float* accb, int bid) {
    int tid = threadIdx.x;
    float rth, delta;
    dev_ri(sm, Rpart, &rth, &delta);
    __syncthreads();
    int tx = tid & 15, ty = tid >> 4;
    int a0 = (bid >> 4) * 64, b0 = (bid & 15) * 64;
    int r0 = tid >> 4, c4 = (tid & 15) << 2;
    float acc[2][4] = {};
    for (int kc = 0; kc < 128; kc += 32) {
        v4f av, bv;
        cld4_2(av, bv, &Qt[(kc + r0) * 1024 + a0 + c4],
               &Qt[(kc + r0) * 1024 + b0 + c4]);
        *(v4f*)&sm->tb.As[r0][c4] = av;
        *(v4f*)&sm->tb.Bs[r0][c4] = bv;
        __syncthreads();
        for (int k = 0; k < 32; ++k) {
            float2 a2 = *(const float2*)&sm->tb.As[k][ty * 2];
            float4 b4 = *(const float4*)&sm->tb.Bs[k][tx * 4];
            acc[0][0] += a2.x * b4.x; acc[0][1] += a2.x * b4.y;
            acc[0][2] += a2.x * b4.z; acc[0][3] += a2.x * b4.w;
            acc[1][0] += a2.y * b4.x; acc[1][1] += a2.y * b4.y;
            acc[1][2] += a2.y * b4.z; acc[1][3] += a2.y * b4.w;
        }
        __syncthreads();
    }
    float rib[4];
    #pragma unroll
    for (int j = 0; j < 4; ++j) {
        int bb = b0 + tx * 4 + j;
        v4f t0, t1, t2, t3;
        cld4_4(t0, t1, t2, t3, &Rpart[bb * 16], &Rpart[bb * 16 + 4],
               &Rpart[bb * 16 + 8], &Rpart[bb * 16 + 12]);
        float s = 0.f;
        s += t0.x; s += t0.y; s += t0.z; s += t0.w;
        s += t1.x; s += t1.y; s += t1.z; s += t1.w;
        s += t2.x; s += t2.y; s += t2.z; s += t2.w;
        s += t3.x; s += t3.y; s += t3.z; s += t3.w;
        rib[j] = s;
    }
    float s = 0.f;
    #pragma unroll
    for (int i = 0; i < 2; ++i) {
        int aa = a0 + ty * 2 + i;
        v4f t0, t1, t2, t3;
        cld4_4(t0, t1, t2, t3, &Rpart[aa * 16], &Rpart[aa * 16 + 4],
               &Rpart[aa * 16 + 8], &Rpart[aa * 16 + 12]);
        float ria = 0.f;
        ria += t0.x; ria += t0.y; ria += t0.z; ria += t0.w;
        ria += t1.x; ria += t1.y; ria += t1.z; ria += t1.w;
        ria += t2.x; ria += t2.y; ria += t2.z; ria += t2.w;
        ria += t3.x; ria += t3.y; ria += t3.z; ria += t3.w;
        float g0, g1, g2, g3;
        const float* gp = &G[aa * 1024 + b0 + tx * 4];
        cld1_4(g0, g1, g2, g3, gp, gp + 1, gp + 2, gp + 3);
        float gv[4] = {g0, g1, g2, g3};
        #pragma unroll
        for (int j = 0; j < 4; ++j) {
            int bb = b0 + tx * 4 + j;
            float g = gv[j];
            float sg = delta * ((g > 0.f) ? 1.f : ((g < 0.f) ? -1.f : 0.f));
            float ga = (ria > rth) ? sg : g;
            float gb = (rib[j] > rth) ? sg : g;
            float gp2 = (aa == bb) ? g : 0.5f * (ga + gb);
            s += gp2 * acc[i][j];
        }
    }
    __syncthreads();
    sm->tb.red[tid] = s;
    __syncthreads();
    for (int w = 256; w > 0; w >>= 1) {
        if (tid < w) sm->tb.red[tid] += sm->tb.red[tid + w];
        __syncthreads();
    }
    if (tid == 0) atomicAdd(&accb[2], sm->tb.red[0]);
}

__global__ __launch_bounds__(512) void mega(const float* __restrict__ t1,
                                            const float* __restrict__ t2,
                                            const float* __restrict__ params,
                                            const float* __restrict__ tmin,
                                            const float* __restrict__ tmax,
                                            const float* __restrict__ beta,
                                            const float* __restrict__ R,
                                            float* ws, float* out) {
    float* G     = ws + OFF_G;
    float* Qt    = ws + OFF_QT;
    float* Y     = ws + OFF_Y;
    float* C     = ws + OFF_C;
    float* Rpart = ws + OFF_RP;
    float* accb  = ws + OFF_ACC;
    unsigned* bb = (unsigned*)(ws + OFF_BAR);
    __shared__ Smem sm;
    int bid = blockIdx.x;
    int tid = threadIdx.x;
    unsigned phA = 0, phB = 0, phC = 0, phE = 0;

    // P0a: zero C (blocks 0-31); stats elsewhere
    if (bid < 32) {
        ast(&C[bid * 512 + tid], 0.f);
    } else if (bid < 250) dev_match(&sm, t1, t2, accb, bid - 32);
    else if (bid == 250) dev_range(&sm, params, tmin, tmax, accb);
    else if (bid < 255) dev_sumsq(&sm, R, accb, bid - 251);
    ++phC;
    if (bid < 32) {
        bar_arrive(bb, BAR_C + (bid >> 2));
        bar_wait(bb, BAR_C, 8, phC * 4);
        dev_syrk(&sm, R, R, C, bid);
    }
    ++phC;
    if (bid < 32) bar_arrive(bb, BAR_C + (bid >> 2));
    if (bid < 16) {
        bar_wait(bb, BAR_C, 8, phC * 4);
        dev_cholTrsm(&sm, C, R, Qt, bid);
    }
    ++phE;
    if (bid < 16) bar_arrive(bb, BAR_E + (bid >> 2));
    bar_wait(bb, BAR_E, 4, phE * 4);

    for (int it = 0; it < 50; ++it) {
        dev_gemmG(&sm, Qt, G, Rpart, bid);
        // zero Y (all blocks) and C (blocks 0-31) for this iteration's consumers
        ast(&Y[bid * 512 + tid], 0.f);
        if (bid < 32) ast(&C[bid * 512 + tid], 0.f);
        ++phA;
        bar_arrive(bb, BAR_A + (bid & 63));
        bar_wait(bb, BAR_A, 64, phA * 4);
        {
            float rth, delta;
            dev_ri(&sm, Rpart, &rth, &delta);
            dev_gemmY(&sm, Qt, G, rth, delta, Y, bid);
        }
        ++phB;
        bar_arrive(bb, BAR_B + (bid & 63));
        if (bid < 32) {
            bar_wait(bb, BAR_B, 64, phB * 4);
            dev_syrk(&sm, Y, Y, C, bid);
        }
        ++phC;
        if (bid < 32) bar_arrive(bb, BAR_C + (bid >> 2));
        if (bid < 16) {
            bar_wait(bb, BAR_C, 8, phC * 4);
            dev_cholTrsm(&sm, C, Y, Qt, bid);
        }
        ++phE;
        if (bid < 16) bar_arrive(bb, BAR_E + (bid >> 2));
        bar_wait(bb, BAR_E, 4, phE * 4);
    }

    dev_trB(&sm, Qt, G, Rpart, accb, bid);
    ++phA;
    bar_arrive(bb, BAR_A + (bid & 63));
    if (bid == 0) {
        bar_wait(bb, BAR_A, 64, phA * 4);
        if (tid == 0)
            out[0] = ald(&accb[0]) / 4194304.f + beta[0] * (ald(&accb[1]) / 2176.f)
                   + (ald(&accb[2]) + ald(&accb[3])) / 131072.f;
    }
}

extern "C" void kernel_launch(void* const* d_in, const int* in_sizes, int n_in,
                              void* d_out, int out_size, void* d_ws, size_t ws_size,
                              hipStream_t stream) {
    const float* t1 = (const float*)d_in[0];
    const float* t2 = (const float*)d_in[1];
    const float* params = (const float*)d_in[2];
    const float* tmin = (const float*)d_in[3];
    const float* tmax = (const float*)d_in[4];
    const float* beta = (const float*)d_in[5];
    const float* R = (const float*)d_in[6];
    float* ws = (float*)d_ws;
    float* out = (float*)d_out;

    // zero accumulators + barrier counter lines (144 lines * 64B + 64B acc)
    hipMemsetAsync(ws + OFF_ACC, 0, 9280, stream);
    mega<<<NBLK, NTHR, 0, stream>>>(t1, t2, params, tmin, tmax, beta, R, ws, out);
}